// Round 9
// baseline (573.436 us; speedup 1.0000x reference)
//
#include <hip/hip_runtime.h>
#include <hip/hip_fp16.h>

#define NN 100000
#define NE 3200000
#define NG 128
#define HID 64

#define BSH 9                       // nodes per bucket = 512
#define BNODES 512
#define NBK ((NN + BNODES - 1) / BNODES)   // 196
#define CCH 4096                    // edges staged per block in bscatter

typedef __attribute__((ext_vector_type(2))) _Float16 half2v;
typedef __attribute__((ext_vector_type(4))) _Float16 half4v;
typedef __attribute__((ext_vector_type(8))) _Float16 half8v;

#if __has_builtin(__builtin_amdgcn_fdot2)
#define FDOT2(v, o, a) __builtin_amdgcn_fdot2((v), (o), (a), false)
#else
static __device__ inline float FDOT2(half2v v, half2v o, float a) {
    return a + (float)v.x * (float)o.x + (float)v.y * (float)o.y;
}
#endif

// ---------------- bucket count: hist of dst>>BSH ----------------
__global__ __launch_bounds__(256) void bcount_kernel(const int* __restrict__ dst,
                                                     int* __restrict__ bcnt, int E) {
    __shared__ int h[NBK];
    for (int i = threadIdx.x; i < NBK; i += 256) h[i] = 0;
    __syncthreads();
    for (int e = blockIdx.x * 256 + threadIdx.x; e < E; e += gridDim.x * 256)
        atomicAdd(&h[dst[e] >> BSH], 1);
    __syncthreads();
    for (int i = threadIdx.x; i < NBK; i += 256)
        if (h[i]) atomicAdd(&bcnt[i], h[i]);
}

// ---------------- bucket scan (196 values, 1 block) ----------------
__global__ __launch_bounds__(256) void bscan_kernel(const int* __restrict__ bcnt,
                                                    int* __restrict__ bbase,
                                                    int* __restrict__ bcur, int E) {
    __shared__ int s[NBK];
    int t = threadIdx.x;
    if (t < NBK) s[t] = bcnt[t];
    __syncthreads();
    if (t == 0) {
        int acc = 0;
        for (int i = 0; i < NBK; ++i) { int v = s[i]; s[i] = acc; acc += v; }
    }
    __syncthreads();
    if (t < NBK) { bbase[t] = s[t]; bcur[t] = s[t]; }
    if (t == 0) bbase[NBK] = E;
}

// ---------------- scatter packed (dstLocal<<17 | src) into bucket order -----
__global__ __launch_bounds__(256) void bscatter_kernel(const int* __restrict__ src,
                                                       const int* __restrict__ dst,
                                                       int* __restrict__ bcur,
                                                       unsigned* __restrict__ pairs,
                                                       int E) {
    __shared__ unsigned stage[CCH];      // 16 KB
    __shared__ unsigned char bb[CCH];    // 4 KB
    __shared__ int cnt[NBK];
    __shared__ int base[NBK];
    const int e0 = blockIdx.x * CCH;
    const int n  = min(CCH, E - e0);
    if (n <= 0) return;
    for (int i = threadIdx.x; i < NBK; i += 256) cnt[i] = 0;
    __syncthreads();
    for (int i = threadIdx.x; i < n; i += 256) {
        int s = src[e0 + i], d = dst[e0 + i];
        int b = d >> BSH;
        stage[i] = ((unsigned)(d & (BNODES - 1)) << 17) | (unsigned)s;
        bb[i] = (unsigned char)b;
        atomicAdd(&cnt[b], 1);
    }
    __syncthreads();
    for (int i = threadIdx.x; i < NBK; i += 256) {
        int c = cnt[i];
        base[i] = c ? atomicAdd(&bcur[i], c) : 0;
        cnt[i] = 0;                 // reuse as local cursor
    }
    __syncthreads();
    for (int i = threadIdx.x; i < n; i += 256) {
        int b = bb[i];
        int pos = base[b] + atomicAdd(&cnt[b], 1);
        pairs[pos] = stage[i];
    }
}

// ---------------- per-bucket CSR build: rowptr, dis, csr_src ----------------
__global__ __launch_bounds__(256) void csr_kernel(const unsigned* __restrict__ pairs,
                                                  const int* __restrict__ bbase,
                                                  int* __restrict__ rowptr,
                                                  int* __restrict__ csr_src,
                                                  float* __restrict__ dis,
                                                  int N, int E) {
    __shared__ int hist[BNODES];
    __shared__ int cur[BNODES];
    __shared__ int s[256];
    const int b     = blockIdx.x;
    const int t     = threadIdx.x;
    const int node0 = b << BSH;
    const int nn    = min(BNODES, N - node0);
    const int p0 = bbase[b], p1 = bbase[b + 1];

    for (int i = t; i < BNODES; i += 256) hist[i] = 0;
    __syncthreads();
    for (int i = p0 + t; i < p1; i += 256)
        atomicAdd(&hist[pairs[i] >> 17], 1);
    __syncthreads();

    int h0 = hist[2 * t], h1 = hist[2 * t + 1];
    int v = h0 + h1;
    s[t] = v;
    __syncthreads();
    for (int off = 1; off < 256; off <<= 1) {
        int u = (t >= off) ? s[t - off] : 0;
        __syncthreads();
        s[t] += u;
        __syncthreads();
    }
    int excl = s[t] - v;
    int e0 = p0 + excl;
    int e1 = e0 + h0;
    if (2 * t < nn) {
        rowptr[node0 + 2 * t] = e0;
        dis[node0 + 2 * t] = rsqrtf((float)h0 + 1.0f);
        cur[2 * t] = e0;
    }
    if (2 * t + 1 < nn) {
        rowptr[node0 + 2 * t + 1] = e1;
        dis[node0 + 2 * t + 1] = rsqrtf((float)h1 + 1.0f);
        cur[2 * t + 1] = e1;
    }
    if (b == NBK - 1 && t == 0) rowptr[N] = E;
    __syncthreads();

    for (int i = p0 + t; i < p1; i += 256) {
        unsigned p = pairs[i];
        int pos = atomicAdd(&cur[p >> 17], 1);
        csr_src[pos] = (int)(p & 0x1FFFFu);
    }
}

// ---------------- x16h prep: fp16( x[i,k]*dis[i] ), 0 pad -------------------
__global__ __launch_bounds__(256) void xprep_kernel(const float* __restrict__ x,
                                                    const float* __restrict__ dis,
                                                    __half* __restrict__ x16h, int N) {
    int gid = blockIdx.x * 256 + threadIdx.x;
    if (gid >= N * 16) return;
    int node = gid >> 4, k = gid & 15;
    float v = (k < 15) ? x[node * 15 + k] * dis[node] : 0.0f;
    x16h[gid] = __float2half(v);
}

// ---------------- gather16: aggx = P_hat*(x*dis)  (4 lanes x 8B per node) ---
__global__ __launch_bounds__(256) void gather16_kernel(const half4v* __restrict__ xh,
                                                       const int* __restrict__ csr_src,
                                                       const int* __restrict__ rowptr,
                                                       const float* __restrict__ dis,
                                                       float4* __restrict__ aggx, int N) {
    const int gid  = blockIdx.x * 256 + threadIdx.x;
    const int node = gid >> 2;
    if (node >= N) return;
    const int l  = threadIdx.x & 3;
    const int gb = threadIdx.x & 60;
    const int start = rowptr[node], end = rowptr[node + 1];
    const half2v ONEX = {(_Float16)1.0f, (_Float16)0.0f};
    const half2v ONEY = {(_Float16)0.0f, (_Float16)1.0f};
    float a0 = 0.0f, a1 = 0.0f, a2 = 0.0f, a3 = 0.0f;
    for (int j0 = start; j0 < end; j0 += 4) {
        int j   = j0 + l;
        int s   = (j < end) ? csr_src[j] : 0;
        int cnt = min(4, end - j0);
#pragma unroll
        for (int k = 0; k < 4; ++k) {
            int sk = __shfl(s, gb + k);
            if (k < cnt) {
                half4v v = xh[sk * 4 + l];
                half2v p0 = __builtin_shufflevector(v, v, 0, 1);
                half2v p1 = __builtin_shufflevector(v, v, 2, 3);
                a0 = FDOT2(p0, ONEX, a0);
                a1 = FDOT2(p0, ONEY, a1);
                a2 = FDOT2(p1, ONEX, a2);
                a3 = FDOT2(p1, ONEY, a3);
            }
        }
    }
    half4v sv = xh[node * 4 + l];
    half2v s0 = __builtin_shufflevector(sv, sv, 0, 1);
    half2v s1 = __builtin_shufflevector(sv, sv, 2, 3);
    a0 += (float)s0.x; a1 += (float)s0.y;
    a2 += (float)s1.x; a3 += (float)s1.y;
    float sn = dis[node];
    aggx[(size_t)node * 4 + l] = make_float4(sn * a0, sn * a1, sn * a2, sn * a3);
}

// ---------------- gemm1: h1pre = aggx @ W1  (fp32 out) ----------------------
__global__ __launch_bounds__(256) void gemm1_kernel(const float* __restrict__ in,
                                                    const float* __restrict__ w,
                                                    float* __restrict__ h1pre, int N) {
    __shared__ float w_s[16 * 64];
    __shared__ float in_s[64 * 17];
    const int tid  = threadIdx.x;
    const int row0 = blockIdx.x * 64;
    const int rows = min(64, N - row0);

    for (int i = tid; i < 16 * 64; i += 256) w_s[i] = (i < 15 * 64) ? w[i] : 0.0f;
    for (int i = tid; i < rows * 16; i += 256) {
        int r = i >> 4, k = i & 15;
        in_s[r * 17 + k] = in[(size_t)(row0 + r) * 16 + k];
    }
    __syncthreads();

    const int r  = tid & 63;
    const int cg = tid >> 6;
    float acc[16];
#pragma unroll
    for (int i = 0; i < 16; ++i) acc[i] = 0.0f;
#pragma unroll
    for (int k = 0; k < 16; ++k) {
        float a = in_s[r * 17 + k];
#pragma unroll
        for (int cc = 0; cc < 16; ++cc)
            acc[cc] += a * w_s[k * 64 + cg * 16 + cc];
    }
    const int row = row0 + r;
    if (row < N) {
        float* hp = h1pre + (size_t)row * HID + cg * 16;
#pragma unroll
        for (int v4 = 0; v4 < 4; ++v4)
            reinterpret_cast<float4*>(hp)[v4] =
                make_float4(acc[4 * v4], acc[4 * v4 + 1],
                            acc[4 * v4 + 2], acc[4 * v4 + 3]);
    }
}

// ---------------- gemmB: th = fp16( relu(in+bias) @ w * dis ) ---------------
__global__ __launch_bounds__(256) void gemmB_kernel(const float* __restrict__ in,
                                                    const float* __restrict__ w,
                                                    const float* __restrict__ bias,
                                                    const float* __restrict__ dis,
                                                    __half* __restrict__ t, int N) {
    __shared__ float w_s[64 * 64];
    __shared__ float in_s[64 * 65];
    const int tid  = threadIdx.x;
    const int row0 = blockIdx.x * 64;
    const int rows = min(64, N - row0);

    for (int i = tid; i < 64 * 64; i += 256) w_s[i] = w[i];
    for (int i = tid; i < rows * 64; i += 256) {
        int r = i >> 6, k = i & 63;
        float v = in[(size_t)(row0 + r) * 64 + k];
        in_s[r * 65 + k] = fmaxf(v + bias[k], 0.0f);
    }
    __syncthreads();

    const int r  = tid & 63;
    const int cg = tid >> 6;
    const float2* w2 = reinterpret_cast<const float2*>(w_s);
    float2 acc2[8];
#pragma unroll
    for (int i = 0; i < 8; ++i) acc2[i] = make_float2(0.0f, 0.0f);
#pragma unroll
    for (int k = 0; k < 64; ++k) {
        float a = in_s[r * 65 + k];
        const float2* wk = w2 + k * 32 + cg * 8;
#pragma unroll
        for (int i = 0; i < 8; ++i) {
            float2 wv = wk[i];
            acc2[i].x += a * wv.x;
            acc2[i].y += a * wv.y;
        }
    }
    const int row = row0 + r;
    if (row < N) {
        float sd = dis[row];
        __align__(16) __half2 hh[8];
#pragma unroll
        for (int i = 0; i < 8; ++i)
            hh[i] = __floats2half2_rn(acc2[i].x * sd, acc2[i].y * sd);
        float4* tp = reinterpret_cast<float4*>(t + (size_t)row * HID + cg * 16);
        tp[0] = reinterpret_cast<float4*>(hh)[0];
        tp[1] = reinterpret_cast<float4*>(hh)[1];
    }
}

// ---------------- gatherh (fp16 table): 8 lanes x 16B per node --------------
// agg[d,:] = dis[d] * (t[d,:] + sum t[src,:]) ; exact fp32 accumulate (fdot2)
__global__ __launch_bounds__(256) void gatherh_kernel(const half8v* __restrict__ thv,
                                                      const int* __restrict__ csr_src,
                                                      const int* __restrict__ rowptr,
                                                      const float* __restrict__ dis,
                                                      float4* __restrict__ agg, int N) {
    const int gid  = blockIdx.x * 256 + threadIdx.x;
    const int node = gid >> 3;
    if (node >= N) return;
    const int l  = threadIdx.x & 7;
    const int gb = threadIdx.x & 56;
    const int start = rowptr[node], end = rowptr[node + 1];
    const half2v ONEX = {(_Float16)1.0f, (_Float16)0.0f};
    const half2v ONEY = {(_Float16)0.0f, (_Float16)1.0f};
    float a0 = 0, a1 = 0, a2 = 0, a3 = 0, a4 = 0, a5 = 0, a6 = 0, a7 = 0;
    for (int j0 = start; j0 < end; j0 += 8) {
        int j   = j0 + l;
        int s   = (j < end) ? csr_src[j] : 0;
        int cnt = min(8, end - j0);
#pragma unroll
        for (int k = 0; k < 8; ++k) {
            int sk = __shfl(s, gb + k);
            if (k < cnt) {
                half8v v = thv[sk * 8 + l];
                half2v p0 = __builtin_shufflevector(v, v, 0, 1);
                half2v p1 = __builtin_shufflevector(v, v, 2, 3);
                half2v p2 = __builtin_shufflevector(v, v, 4, 5);
                half2v p3 = __builtin_shufflevector(v, v, 6, 7);
                a0 = FDOT2(p0, ONEX, a0);
                a1 = FDOT2(p0, ONEY, a1);
                a2 = FDOT2(p1, ONEX, a2);
                a3 = FDOT2(p1, ONEY, a3);
                a4 = FDOT2(p2, ONEX, a4);
                a5 = FDOT2(p2, ONEY, a5);
                a6 = FDOT2(p3, ONEX, a6);
                a7 = FDOT2(p3, ONEY, a7);
            }
        }
    }
    half8v sv = thv[node * 8 + l];
    half2v q0 = __builtin_shufflevector(sv, sv, 0, 1);
    half2v q1 = __builtin_shufflevector(sv, sv, 2, 3);
    half2v q2 = __builtin_shufflevector(sv, sv, 4, 5);
    half2v q3 = __builtin_shufflevector(sv, sv, 6, 7);
    a0 += (float)q0.x; a1 += (float)q0.y;
    a2 += (float)q1.x; a3 += (float)q1.y;
    a4 += (float)q2.x; a5 += (float)q2.y;
    a6 += (float)q3.x; a7 += (float)q3.y;
    float sn = dis[node];
    agg[(size_t)node * 16 + l * 2]     = make_float4(sn * a0, sn * a1, sn * a2, sn * a3);
    agg[(size_t)node * 16 + l * 2 + 1] = make_float4(sn * a4, sn * a5, sn * a6, sn * a7);
}

// ---------------- mean pool (batch is sorted) ------------------------------
__global__ __launch_bounds__(256) void pool_kernel(const float* __restrict__ agg,
                                                   const float* __restrict__ b4,
                                                   const int* __restrict__ batch,
                                                   float* __restrict__ sums,
                                                   float* __restrict__ cnts, int N) {
    __shared__ float lsum[NG * HID];
    __shared__ float lcnt[NG];
    const int tid  = threadIdx.x;
    const int base = blockIdx.x * 256;
    const int last = min(base + 256, N) - 1;
    const int gfirst = batch[base];
    const int glast  = batch[last];
    const int span   = glast - gfirst + 1;

    for (int i = tid; i < span * HID; i += 256) lsum[i] = 0.0f;
    for (int i = tid; i < span; i += 256) lcnt[i] = 0.0f;
    __syncthreads();

    const int f = tid & 63, sub = tid >> 6;
    for (int n = base + sub; n < min(base + 256, N); n += 4) {
        int g = batch[n];
        float v = fmaxf(agg[(size_t)n * HID + f] + b4[f], 0.0f);
        atomicAdd(&lsum[(g - gfirst) * HID + f], v);
        if (f == 0) atomicAdd(&lcnt[g - gfirst], 1.0f);
    }
    __syncthreads();

    for (int i = tid; i < span * HID; i += 256)
        atomicAdd(&sums[(size_t)gfirst * HID + i], lsum[i]);
    for (int i = tid; i < span; i += 256) atomicAdd(&cnts[gfirst + i], lcnt[i]);
}

__global__ __launch_bounds__(256) void finalize_kernel(const float* __restrict__ sums,
                                                       const float* __restrict__ cnts,
                                                       float* __restrict__ out) {
    int i = blockIdx.x * 256 + threadIdx.x;
    if (i < NG * HID) out[i] = sums[i] / fmaxf(cnts[i >> 6], 1.0f);
}

// ---------------- launch ----------------
extern "C" void kernel_launch(void* const* d_in, const int* in_sizes, int n_in,
                              void* d_out, int out_size, void* d_ws, size_t ws_size,
                              hipStream_t stream) {
    const float* x  = (const float*)d_in[0];
    const float* w1 = (const float*)d_in[1];
    const float* b1 = (const float*)d_in[2];
    const float* w2 = (const float*)d_in[3];
    const float* b2 = (const float*)d_in[4];
    const float* w3 = (const float*)d_in[5];
    const float* b3 = (const float*)d_in[6];
    const float* w4 = (const float*)d_in[7];
    const float* b4 = (const float*)d_in[8];
    const int* ei    = (const int*)d_in[9];
    const int* batch = (const int*)d_in[10];
    const int* src = ei;
    const int* dst = ei + NE;

    // workspace layout:
    //   AGG (25.6 MB fp32) also serves as h1pre
    //   region (22.4 MB): pairs (12.8, dead after csr) overlaps x16h|aggx|th
    float*    AGG     = (float*)d_ws;                        // NN*HID fp32
    float*    h1pre   = AGG;
    unsigned* pairs   = (unsigned*)(AGG + (size_t)NN * HID); // NE uint (12.8 MB)
    __half*   x16h    = (__half*)pairs;                      // NN*16 fp16 (3.2 MB)
    float*    aggx    = (float*)(x16h + (size_t)NN * 16);    // NN*16 fp32 (6.4 MB)
    __half*   th      = (__half*)(aggx + (size_t)NN * 16);   // NN*HID fp16 (12.8 MB)
    int*      csr_src = (int*)(th + (size_t)NN * HID);       // NE
    int*      rowptr  = csr_src + NE;                        // NN+1
    float*    dis     = (float*)(rowptr + NN + 1);           // NN
    int*      bcnt    = (int*)(dis + NN);                    // NBK
    int*      bbase   = bcnt + NBK;                          // NBK+1
    int*      bcur    = bbase + NBK + 1;                     // NBK
    float*    sums    = (float*)(bcur + NBK);                // NG*HID
    float*    cnts    = sums + NG * HID;                     // NG

    float* out = (float*)d_out;

    const int NB  = (NN + 255) / 256;
    const int GB  = (NN + 63) / 64;
    const int XB  = (NN * 16 + 255) / 256;   // xprep
    const int OB  = (NN * 4 + 255) / 256;    // gather16: 4 lanes/node
    const int HB  = (NN * 8 + 255) / 256;    // gatherh: 8 lanes/node
    const int CB  = (NE + CCH - 1) / CCH;

    hipMemsetAsync(bcnt, 0, NBK * sizeof(int), stream);
    hipMemsetAsync(sums, 0, (NG * HID + NG) * sizeof(float), stream);

    bcount_kernel<<<512, 256, 0, stream>>>(dst, bcnt, NE);
    bscan_kernel<<<1, 256, 0, stream>>>(bcnt, bbase, bcur, NE);
    bscatter_kernel<<<CB, 256, 0, stream>>>(src, dst, bcur, pairs, NE);
    csr_kernel<<<NBK, 256, 0, stream>>>(pairs, bbase, rowptr, csr_src, dis, NN, NE);

    // layer 1 (commuted): aggx = P_hat*(x*dis row-scaled) ; h1pre = aggx @ W1
    xprep_kernel<<<XB, 256, 0, stream>>>(x, dis, x16h, NN);
    gather16_kernel<<<OB, 256, 0, stream>>>((const half4v*)x16h, csr_src, rowptr, dis,
                                            (float4*)aggx, NN);
    gemm1_kernel<<<GB, 256, 0, stream>>>(aggx, w1, h1pre, NN);
    // layers 2..4
    gemmB_kernel<<<GB, 256, 0, stream>>>(h1pre, w2, b1, dis, th, NN);
    gatherh_kernel<<<HB, 256, 0, stream>>>((const half8v*)th, csr_src, rowptr, dis,
                                           (float4*)AGG, NN);
    gemmB_kernel<<<GB, 256, 0, stream>>>(AGG, w3, b2, dis, th, NN);
    gatherh_kernel<<<HB, 256, 0, stream>>>((const half8v*)th, csr_src, rowptr, dis,
                                           (float4*)AGG, NN);
    gemmB_kernel<<<GB, 256, 0, stream>>>(AGG, w4, b3, dis, th, NN);
    gatherh_kernel<<<HB, 256, 0, stream>>>((const half8v*)th, csr_src, rowptr, dis,
                                           (float4*)AGG, NN);

    pool_kernel<<<NB, 256, 0, stream>>>(AGG, b4, batch, sums, cnts, NN);
    finalize_kernel<<<(NG * HID + 255) / 256, 256, 0, stream>>>(sums, cnts, out);
}

// Round 10
// 552.632 us; speedup vs baseline: 1.0376x; 1.0376x over previous
//
#include <hip/hip_runtime.h>
#include <hip/hip_fp16.h>

#define NN 100000
#define NE 3200000
#define NG 128
#define HID 64

#define BSH 9                       // nodes per bucket = 512
#define BNODES 512
#define NBK ((NN + BNODES - 1) / BNODES)   // 196
#define CCH 4096                    // edges staged per block in bscatter

typedef __attribute__((ext_vector_type(2))) _Float16 half2v;
typedef __attribute__((ext_vector_type(4))) _Float16 half4v;

#if __has_builtin(__builtin_amdgcn_fdot2)
#define FDOT2(v, o, a) __builtin_amdgcn_fdot2((v), (o), (a), false)
#else
static __device__ inline float FDOT2(half2v v, half2v o, float a) {
    return a + (float)v.x * (float)o.x + (float)v.y * (float)o.y;
}
#endif

// ---------------- bucket count: hist of dst>>BSH ----------------
__global__ __launch_bounds__(256) void bcount_kernel(const int* __restrict__ dst,
                                                     int* __restrict__ bcnt, int E) {
    __shared__ int h[NBK];
    for (int i = threadIdx.x; i < NBK; i += 256) h[i] = 0;
    __syncthreads();
    for (int e = blockIdx.x * 256 + threadIdx.x; e < E; e += gridDim.x * 256)
        atomicAdd(&h[dst[e] >> BSH], 1);
    __syncthreads();
    for (int i = threadIdx.x; i < NBK; i += 256)
        if (h[i]) atomicAdd(&bcnt[i], h[i]);
}

// ---------------- bucket scan (196 values, 1 block) ----------------
__global__ __launch_bounds__(256) void bscan_kernel(const int* __restrict__ bcnt,
                                                    int* __restrict__ bbase,
                                                    int* __restrict__ bcur, int E) {
    __shared__ int s[NBK];
    int t = threadIdx.x;
    if (t < NBK) s[t] = bcnt[t];
    __syncthreads();
    if (t == 0) {
        int acc = 0;
        for (int i = 0; i < NBK; ++i) { int v = s[i]; s[i] = acc; acc += v; }
    }
    __syncthreads();
    if (t < NBK) { bbase[t] = s[t]; bcur[t] = s[t]; }
    if (t == 0) bbase[NBK] = E;
}

// ---------------- scatter packed (dstLocal<<17 | src) into bucket order -----
__global__ __launch_bounds__(256) void bscatter_kernel(const int* __restrict__ src,
                                                       const int* __restrict__ dst,
                                                       int* __restrict__ bcur,
                                                       unsigned* __restrict__ pairs,
                                                       int E) {
    __shared__ unsigned stage[CCH];      // 16 KB
    __shared__ unsigned char bb[CCH];    // 4 KB
    __shared__ int cnt[NBK];
    __shared__ int base[NBK];
    const int e0 = blockIdx.x * CCH;
    const int n  = min(CCH, E - e0);
    if (n <= 0) return;
    for (int i = threadIdx.x; i < NBK; i += 256) cnt[i] = 0;
    __syncthreads();
    for (int i = threadIdx.x; i < n; i += 256) {
        int s = src[e0 + i], d = dst[e0 + i];
        int b = d >> BSH;
        stage[i] = ((unsigned)(d & (BNODES - 1)) << 17) | (unsigned)s;
        bb[i] = (unsigned char)b;
        atomicAdd(&cnt[b], 1);
    }
    __syncthreads();
    for (int i = threadIdx.x; i < NBK; i += 256) {
        int c = cnt[i];
        base[i] = c ? atomicAdd(&bcur[i], c) : 0;
        cnt[i] = 0;                 // reuse as local cursor
    }
    __syncthreads();
    for (int i = threadIdx.x; i < n; i += 256) {
        int b = bb[i];
        int pos = base[b] + atomicAdd(&cnt[b], 1);
        pairs[pos] = stage[i];
    }
}

// ---------------- per-bucket CSR build: rowptr, dis, csr_src ----------------
__global__ __launch_bounds__(256) void csr_kernel(const unsigned* __restrict__ pairs,
                                                  const int* __restrict__ bbase,
                                                  int* __restrict__ rowptr,
                                                  int* __restrict__ csr_src,
                                                  float* __restrict__ dis,
                                                  int N, int E) {
    __shared__ int hist[BNODES];
    __shared__ int cur[BNODES];
    __shared__ int s[256];
    const int b     = blockIdx.x;
    const int t     = threadIdx.x;
    const int node0 = b << BSH;
    const int nn    = min(BNODES, N - node0);
    const int p0 = bbase[b], p1 = bbase[b + 1];

    for (int i = t; i < BNODES; i += 256) hist[i] = 0;
    __syncthreads();
    for (int i = p0 + t; i < p1; i += 256)
        atomicAdd(&hist[pairs[i] >> 17], 1);
    __syncthreads();

    int h0 = hist[2 * t], h1 = hist[2 * t + 1];
    int v = h0 + h1;
    s[t] = v;
    __syncthreads();
    for (int off = 1; off < 256; off <<= 1) {
        int u = (t >= off) ? s[t - off] : 0;
        __syncthreads();
        s[t] += u;
        __syncthreads();
    }
    int excl = s[t] - v;
    int e0 = p0 + excl;
    int e1 = e0 + h0;
    if (2 * t < nn) {
        rowptr[node0 + 2 * t] = e0;
        dis[node0 + 2 * t] = rsqrtf((float)h0 + 1.0f);
        cur[2 * t] = e0;
    }
    if (2 * t + 1 < nn) {
        rowptr[node0 + 2 * t + 1] = e1;
        dis[node0 + 2 * t + 1] = rsqrtf((float)h1 + 1.0f);
        cur[2 * t + 1] = e1;
    }
    if (b == NBK - 1 && t == 0) rowptr[N] = E;
    __syncthreads();

    for (int i = p0 + t; i < p1; i += 256) {
        unsigned p = pairs[i];
        int pos = atomicAdd(&cur[p >> 17], 1);
        csr_src[pos] = (int)(p & 0x1FFFFu);
    }
}

// ---------------- x16h prep: fp16( x[i,k]*dis[i] ), 0 pad -------------------
__global__ __launch_bounds__(256) void xprep_kernel(const float* __restrict__ x,
                                                    const float* __restrict__ dis,
                                                    __half* __restrict__ x16h, int N) {
    int gid = blockIdx.x * 256 + threadIdx.x;
    if (gid >= N * 16) return;
    int node = gid >> 4, k = gid & 15;
    float v = (k < 15) ? x[node * 15 + k] * dis[node] : 0.0f;
    x16h[gid] = __float2half(v);
}

// ---------------- gather16: aggx = P_hat*(x*dis)  (4 lanes x 8B per node) ---
__global__ __launch_bounds__(256) void gather16_kernel(const half4v* __restrict__ xh,
                                                       const int* __restrict__ csr_src,
                                                       const int* __restrict__ rowptr,
                                                       const float* __restrict__ dis,
                                                       float4* __restrict__ aggx, int N) {
    const int gid  = blockIdx.x * 256 + threadIdx.x;
    const int node = gid >> 2;
    if (node >= N) return;
    const int l  = threadIdx.x & 3;
    const int gb = threadIdx.x & 60;
    const int start = rowptr[node], end = rowptr[node + 1];
    const half2v ONEX = {(_Float16)1.0f, (_Float16)0.0f};
    const half2v ONEY = {(_Float16)0.0f, (_Float16)1.0f};
    float a0 = 0.0f, a1 = 0.0f, a2 = 0.0f, a3 = 0.0f;
    for (int j0 = start; j0 < end; j0 += 4) {
        int j   = j0 + l;
        int s   = (j < end) ? csr_src[j] : 0;
        int cnt = min(4, end - j0);
#pragma unroll
        for (int k = 0; k < 4; ++k) {
            int sk = __shfl(s, gb + k);
            if (k < cnt) {
                half4v v = xh[sk * 4 + l];
                half2v p0 = __builtin_shufflevector(v, v, 0, 1);
                half2v p1 = __builtin_shufflevector(v, v, 2, 3);
                a0 = FDOT2(p0, ONEX, a0);
                a1 = FDOT2(p0, ONEY, a1);
                a2 = FDOT2(p1, ONEX, a2);
                a3 = FDOT2(p1, ONEY, a3);
            }
        }
    }
    half4v sv = xh[node * 4 + l];
    half2v s0 = __builtin_shufflevector(sv, sv, 0, 1);
    half2v s1 = __builtin_shufflevector(sv, sv, 2, 3);
    a0 += (float)s0.x; a1 += (float)s0.y;
    a2 += (float)s1.x; a3 += (float)s1.y;
    float sn = dis[node];
    aggx[(size_t)node * 4 + l] = make_float4(sn * a0, sn * a1, sn * a2, sn * a3);
}

// ---------------- gemm1: h1pre = aggx @ W1  (fp32 out) ----------------------
__global__ __launch_bounds__(256) void gemm1_kernel(const float* __restrict__ in,
                                                    const float* __restrict__ w,
                                                    float* __restrict__ h1pre, int N) {
    __shared__ float w_s[16 * 64];
    __shared__ float in_s[64 * 17];
    const int tid  = threadIdx.x;
    const int row0 = blockIdx.x * 64;
    const int rows = min(64, N - row0);

    for (int i = tid; i < 16 * 64; i += 256) w_s[i] = (i < 15 * 64) ? w[i] : 0.0f;
    for (int i = tid; i < rows * 16; i += 256) {
        int r = i >> 4, k = i & 15;
        in_s[r * 17 + k] = in[(size_t)(row0 + r) * 16 + k];
    }
    __syncthreads();

    const int r  = tid & 63;
    const int cg = tid >> 6;
    float acc[16];
#pragma unroll
    for (int i = 0; i < 16; ++i) acc[i] = 0.0f;
#pragma unroll
    for (int k = 0; k < 16; ++k) {
        float a = in_s[r * 17 + k];
#pragma unroll
        for (int cc = 0; cc < 16; ++cc)
            acc[cc] += a * w_s[k * 64 + cg * 16 + cc];
    }
    const int row = row0 + r;
    if (row < N) {
        float* hp = h1pre + (size_t)row * HID + cg * 16;
#pragma unroll
        for (int v4 = 0; v4 < 4; ++v4)
            reinterpret_cast<float4*>(hp)[v4] =
                make_float4(acc[4 * v4], acc[4 * v4 + 1],
                            acc[4 * v4 + 2], acc[4 * v4 + 3]);
    }
}

// ---------------- gemmB: th = fp16( relu(in+bias) @ w * dis ) ---------------
__global__ __launch_bounds__(256) void gemmB_kernel(const float* __restrict__ in,
                                                    const float* __restrict__ w,
                                                    const float* __restrict__ bias,
                                                    const float* __restrict__ dis,
                                                    __half* __restrict__ t, int N) {
    __shared__ float w_s[64 * 64];
    __shared__ float in_s[64 * 65];
    const int tid  = threadIdx.x;
    const int row0 = blockIdx.x * 64;
    const int rows = min(64, N - row0);

    for (int i = tid; i < 64 * 64; i += 256) w_s[i] = w[i];
    for (int i = tid; i < rows * 64; i += 256) {
        int r = i >> 6, k = i & 63;
        float v = in[(size_t)(row0 + r) * 64 + k];
        in_s[r * 65 + k] = fmaxf(v + bias[k], 0.0f);
    }
    __syncthreads();

    const int r  = tid & 63;
    const int cg = tid >> 6;
    const float2* w2 = reinterpret_cast<const float2*>(w_s);
    float2 acc2[8];
#pragma unroll
    for (int i = 0; i < 8; ++i) acc2[i] = make_float2(0.0f, 0.0f);
#pragma unroll
    for (int k = 0; k < 64; ++k) {
        float a = in_s[r * 65 + k];
        const float2* wk = w2 + k * 32 + cg * 8;
#pragma unroll
        for (int i = 0; i < 8; ++i) {
            float2 wv = wk[i];
            acc2[i].x += a * wv.x;
            acc2[i].y += a * wv.y;
        }
    }
    const int row = row0 + r;
    if (row < N) {
        float sd = dis[row];
        __align__(16) __half2 hh[8];
#pragma unroll
        for (int i = 0; i < 8; ++i)
            hh[i] = __floats2half2_rn(acc2[i].x * sd, acc2[i].y * sd);
        float4* tp = reinterpret_cast<float4*>(t + (size_t)row * HID + cg * 16);
        tp[0] = reinterpret_cast<float4*>(hh)[0];
        tp[1] = reinterpret_cast<float4*>(hh)[1];
    }
}

// ---------------- gatherh (fp16 table): 32 lanes/node, 16 loads in flight ---
// agg[d,:] = dis[d] * (t[d,:] + sum t[src,:]) ; exact fp32 accumulate (fdot2)
__global__ __launch_bounds__(256) void gatherh_kernel(const half2v* __restrict__ th,
                                                      const int* __restrict__ csr_src,
                                                      const int* __restrict__ rowptr,
                                                      const float* __restrict__ dis,
                                                      float* __restrict__ agg, int N) {
    const int gid  = blockIdx.x * 256 + threadIdx.x;
    const int node = gid >> 5;
    if (node >= N) return;
    const int l  = threadIdx.x & 31;
    const int hb = threadIdx.x & 32;
    const int start = rowptr[node], end = rowptr[node + 1];
    const half2v* tl = th + l;
    const half2v ONEX = {(_Float16)1.0f, (_Float16)0.0f};
    const half2v ONEY = {(_Float16)0.0f, (_Float16)1.0f};
    float ax = 0.0f, ay = 0.0f;
    for (int j0 = start; j0 < end; j0 += 32) {
        int j   = j0 + l;
        int s   = (j < end) ? csr_src[j] : 0;
        int cnt = min(32, end - j0);
        int k = 0;
        // 16 independent row-loads in flight per iteration (MLP for L3 latency)
        for (; k + 16 <= cnt; k += 16) {
            int sk[16];
#pragma unroll
            for (int u = 0; u < 16; ++u) sk[u] = __shfl(s, hb + k + u);
            half2v v[16];
#pragma unroll
            for (int u = 0; u < 16; ++u) v[u] = tl[sk[u] * 32];
#pragma unroll
            for (int u = 0; u < 16; ++u) {
                ax = FDOT2(v[u], ONEX, ax);
                ay = FDOT2(v[u], ONEY, ay);
            }
        }
        for (; k + 4 <= cnt; k += 4) {
            int s0 = __shfl(s, hb + k);
            int s1 = __shfl(s, hb + k + 1);
            int s2 = __shfl(s, hb + k + 2);
            int s3 = __shfl(s, hb + k + 3);
            half2v v0 = tl[s0 * 32];
            half2v v1 = tl[s1 * 32];
            half2v v2 = tl[s2 * 32];
            half2v v3 = tl[s3 * 32];
            ax = FDOT2(v0, ONEX, ax); ay = FDOT2(v0, ONEY, ay);
            ax = FDOT2(v1, ONEX, ax); ay = FDOT2(v1, ONEY, ay);
            ax = FDOT2(v2, ONEX, ax); ay = FDOT2(v2, ONEY, ay);
            ax = FDOT2(v3, ONEX, ax); ay = FDOT2(v3, ONEY, ay);
        }
        for (; k < cnt; ++k) {
            half2v v = tl[__shfl(s, hb + k) * 32];
            ax += (float)v.x; ay += (float)v.y;
        }
    }
    half2v self = tl[node * 32];
    ax += (float)self.x; ay += (float)self.y;
    float sn = dis[node];
    reinterpret_cast<float2*>(agg)[(size_t)node * 32 + l] =
        make_float2(sn * ax, sn * ay);
}

// ---------------- mean pool (batch is sorted) ------------------------------
__global__ __launch_bounds__(256) void pool_kernel(const float* __restrict__ agg,
                                                   const float* __restrict__ b4,
                                                   const int* __restrict__ batch,
                                                   float* __restrict__ sums,
                                                   float* __restrict__ cnts, int N) {
    __shared__ float lsum[NG * HID];
    __shared__ float lcnt[NG];
    const int tid  = threadIdx.x;
    const int base = blockIdx.x * 256;
    const int last = min(base + 256, N) - 1;
    const int gfirst = batch[base];
    const int glast  = batch[last];
    const int span   = glast - gfirst + 1;

    for (int i = tid; i < span * HID; i += 256) lsum[i] = 0.0f;
    for (int i = tid; i < span; i += 256) lcnt[i] = 0.0f;
    __syncthreads();

    const int f = tid & 63, sub = tid >> 6;
    for (int n = base + sub; n < min(base + 256, N); n += 4) {
        int g = batch[n];
        float v = fmaxf(agg[(size_t)n * HID + f] + b4[f], 0.0f);
        atomicAdd(&lsum[(g - gfirst) * HID + f], v);
        if (f == 0) atomicAdd(&lcnt[g - gfirst], 1.0f);
    }
    __syncthreads();

    for (int i = tid; i < span * HID; i += 256)
        atomicAdd(&sums[(size_t)gfirst * HID + i], lsum[i]);
    for (int i = tid; i < span; i += 256) atomicAdd(&cnts[gfirst + i], lcnt[i]);
}

__global__ __launch_bounds__(256) void finalize_kernel(const float* __restrict__ sums,
                                                       const float* __restrict__ cnts,
                                                       float* __restrict__ out) {
    int i = blockIdx.x * 256 + threadIdx.x;
    if (i < NG * HID) out[i] = sums[i] / fmaxf(cnts[i >> 6], 1.0f);
}

// ---------------- launch ----------------
extern "C" void kernel_launch(void* const* d_in, const int* in_sizes, int n_in,
                              void* d_out, int out_size, void* d_ws, size_t ws_size,
                              hipStream_t stream) {
    const float* x  = (const float*)d_in[0];
    const float* w1 = (const float*)d_in[1];
    const float* b1 = (const float*)d_in[2];
    const float* w2 = (const float*)d_in[3];
    const float* b2 = (const float*)d_in[4];
    const float* w3 = (const float*)d_in[5];
    const float* b3 = (const float*)d_in[6];
    const float* w4 = (const float*)d_in[7];
    const float* b4 = (const float*)d_in[8];
    const int* ei    = (const int*)d_in[9];
    const int* batch = (const int*)d_in[10];
    const int* src = ei;
    const int* dst = ei + NE;

    // workspace layout:
    //   AGG (25.6 MB fp32) also serves as h1pre
    //   region (22.4 MB): pairs (12.8, dead after csr) overlaps x16h|aggx|th
    float*    AGG     = (float*)d_ws;                        // NN*HID fp32
    float*    h1pre   = AGG;
    unsigned* pairs   = (unsigned*)(AGG + (size_t)NN * HID); // NE uint (12.8 MB)
    __half*   x16h    = (__half*)pairs;                      // NN*16 fp16 (3.2 MB)
    float*    aggx    = (float*)(x16h + (size_t)NN * 16);    // NN*16 fp32 (6.4 MB)
    __half*   th      = (__half*)(aggx + (size_t)NN * 16);   // NN*HID fp16 (12.8 MB)
    int*      csr_src = (int*)(th + (size_t)NN * HID);       // NE
    int*      rowptr  = csr_src + NE;                        // NN+1
    float*    dis     = (float*)(rowptr + NN + 1);           // NN
    int*      bcnt    = (int*)(dis + NN);                    // NBK
    int*      bbase   = bcnt + NBK;                          // NBK+1
    int*      bcur    = bbase + NBK + 1;                     // NBK
    float*    sums    = (float*)(bcur + NBK);                // NG*HID
    float*    cnts    = sums + NG * HID;                     // NG

    float* out = (float*)d_out;

    const int NB  = (NN + 255) / 256;
    const int GB  = (NN + 63) / 64;
    const int XB  = (NN * 16 + 255) / 256;   // xprep
    const int OB  = (NN * 4 + 255) / 256;    // gather16: 4 lanes/node
    const int HB  = (NN * 32 + 255) / 256;   // gatherh: 32 lanes/node
    const int CB  = (NE + CCH - 1) / CCH;

    hipMemsetAsync(bcnt, 0, NBK * sizeof(int), stream);
    hipMemsetAsync(sums, 0, (NG * HID + NG) * sizeof(float), stream);

    bcount_kernel<<<512, 256, 0, stream>>>(dst, bcnt, NE);
    bscan_kernel<<<1, 256, 0, stream>>>(bcnt, bbase, bcur, NE);
    bscatter_kernel<<<CB, 256, 0, stream>>>(src, dst, bcur, pairs, NE);
    csr_kernel<<<NBK, 256, 0, stream>>>(pairs, bbase, rowptr, csr_src, dis, NN, NE);

    // layer 1 (commuted): aggx = P_hat*(x*dis row-scaled) ; h1pre = aggx @ W1
    xprep_kernel<<<XB, 256, 0, stream>>>(x, dis, x16h, NN);
    gather16_kernel<<<OB, 256, 0, stream>>>((const half4v*)x16h, csr_src, rowptr, dis,
                                            (float4*)aggx, NN);
    gemm1_kernel<<<GB, 256, 0, stream>>>(aggx, w1, h1pre, NN);
    // layers 2..4
    gemmB_kernel<<<GB, 256, 0, stream>>>(h1pre, w2, b1, dis, th, NN);
    gatherh_kernel<<<HB, 256, 0, stream>>>((const half2v*)th, csr_src, rowptr, dis, AGG, NN);
    gemmB_kernel<<<GB, 256, 0, stream>>>(AGG, w3, b2, dis, th, NN);
    gatherh_kernel<<<HB, 256, 0, stream>>>((const half2v*)th, csr_src, rowptr, dis, AGG, NN);
    gemmB_kernel<<<GB, 256, 0, stream>>>(AGG, w4, b3, dis, th, NN);
    gatherh_kernel<<<HB, 256, 0, stream>>>((const half2v*)th, csr_src, rowptr, dis, AGG, NN);

    pool_kernel<<<NB, 256, 0, stream>>>(AGG, b4, batch, sums, cnts, NN);
    finalize_kernel<<<(NG * HID + 255) / 256, 256, 0, stream>>>(sums, cnts, out);
}

// Round 11
// 527.178 us; speedup vs baseline: 1.0877x; 1.0483x over previous
//
#include <hip/hip_runtime.h>
#include <hip/hip_fp16.h>

#define NN 100000
#define NE 3200000
#define NG 128
#define HID 64

#define BSH 9                       // nodes per bucket = 512
#define BNODES 512
#define NBK ((NN + BNODES - 1) / BNODES)   // 196
#define CCH 4096                    // edges staged per block in bscatter

typedef __attribute__((ext_vector_type(2))) _Float16 half2v;
typedef __attribute__((ext_vector_type(4))) _Float16 half4v;

#if __has_builtin(__builtin_amdgcn_fdot2)
#define FDOT2(v, o, a) __builtin_amdgcn_fdot2((v), (o), (a), false)
#else
static __device__ inline float FDOT2(half2v v, half2v o, float a) {
    return a + (float)v.x * (float)o.x + (float)v.y * (float)o.y;
}
#endif

// ---------------- bucket count: hist of dst>>BSH ----------------
__global__ __launch_bounds__(256) void bcount_kernel(const int* __restrict__ dst,
                                                     int* __restrict__ bcnt, int E) {
    __shared__ int h[NBK];
    for (int i = threadIdx.x; i < NBK; i += 256) h[i] = 0;
    __syncthreads();
    for (int e = blockIdx.x * 256 + threadIdx.x; e < E; e += gridDim.x * 256)
        atomicAdd(&h[dst[e] >> BSH], 1);
    __syncthreads();
    for (int i = threadIdx.x; i < NBK; i += 256)
        if (h[i]) atomicAdd(&bcnt[i], h[i]);
}

// ---------------- bucket scan (196 values, 1 block) ----------------
__global__ __launch_bounds__(256) void bscan_kernel(const int* __restrict__ bcnt,
                                                    int* __restrict__ bbase,
                                                    int* __restrict__ bcur, int E) {
    __shared__ int s[NBK];
    int t = threadIdx.x;
    if (t < NBK) s[t] = bcnt[t];
    __syncthreads();
    if (t == 0) {
        int acc = 0;
        for (int i = 0; i < NBK; ++i) { int v = s[i]; s[i] = acc; acc += v; }
    }
    __syncthreads();
    if (t < NBK) { bbase[t] = s[t]; bcur[t] = s[t]; }
    if (t == 0) bbase[NBK] = E;
}

// ---------------- scatter packed (dstLocal<<17 | src) into bucket order -----
__global__ __launch_bounds__(256) void bscatter_kernel(const int* __restrict__ src,
                                                       const int* __restrict__ dst,
                                                       int* __restrict__ bcur,
                                                       unsigned* __restrict__ pairs,
                                                       int E) {
    __shared__ unsigned stage[CCH];      // 16 KB
    __shared__ unsigned char bb[CCH];    // 4 KB
    __shared__ int cnt[NBK];
    __shared__ int base[NBK];
    const int e0 = blockIdx.x * CCH;
    const int n  = min(CCH, E - e0);
    if (n <= 0) return;
    for (int i = threadIdx.x; i < NBK; i += 256) cnt[i] = 0;
    __syncthreads();
    for (int i = threadIdx.x; i < n; i += 256) {
        int s = src[e0 + i], d = dst[e0 + i];
        int b = d >> BSH;
        stage[i] = ((unsigned)(d & (BNODES - 1)) << 17) | (unsigned)s;
        bb[i] = (unsigned char)b;
        atomicAdd(&cnt[b], 1);
    }
    __syncthreads();
    for (int i = threadIdx.x; i < NBK; i += 256) {
        int c = cnt[i];
        base[i] = c ? atomicAdd(&bcur[i], c) : 0;
        cnt[i] = 0;                 // reuse as local cursor
    }
    __syncthreads();
    for (int i = threadIdx.x; i < n; i += 256) {
        int b = bb[i];
        int pos = base[b] + atomicAdd(&cnt[b], 1);
        pairs[pos] = stage[i];
    }
}

// ---------------- per-bucket CSR build: rowptr, dis, csr_src ----------------
__global__ __launch_bounds__(256) void csr_kernel(const unsigned* __restrict__ pairs,
                                                  const int* __restrict__ bbase,
                                                  int* __restrict__ rowptr,
                                                  int* __restrict__ csr_src,
                                                  float* __restrict__ dis,
                                                  int N, int E) {
    __shared__ int hist[BNODES];
    __shared__ int cur[BNODES];
    __shared__ int s[256];
    const int b     = blockIdx.x;
    const int t     = threadIdx.x;
    const int node0 = b << BSH;
    const int nn    = min(BNODES, N - node0);
    const int p0 = bbase[b], p1 = bbase[b + 1];

    for (int i = t; i < BNODES; i += 256) hist[i] = 0;
    __syncthreads();
    for (int i = p0 + t; i < p1; i += 256)
        atomicAdd(&hist[pairs[i] >> 17], 1);
    __syncthreads();

    int h0 = hist[2 * t], h1 = hist[2 * t + 1];
    int v = h0 + h1;
    s[t] = v;
    __syncthreads();
    for (int off = 1; off < 256; off <<= 1) {
        int u = (t >= off) ? s[t - off] : 0;
        __syncthreads();
        s[t] += u;
        __syncthreads();
    }
    int excl = s[t] - v;
    int e0 = p0 + excl;
    int e1 = e0 + h0;
    if (2 * t < nn) {
        rowptr[node0 + 2 * t] = e0;
        dis[node0 + 2 * t] = rsqrtf((float)h0 + 1.0f);
        cur[2 * t] = e0;
    }
    if (2 * t + 1 < nn) {
        rowptr[node0 + 2 * t + 1] = e1;
        dis[node0 + 2 * t + 1] = rsqrtf((float)h1 + 1.0f);
        cur[2 * t + 1] = e1;
    }
    if (b == NBK - 1 && t == 0) rowptr[N] = E;
    __syncthreads();

    for (int i = p0 + t; i < p1; i += 256) {
        unsigned p = pairs[i];
        int pos = atomicAdd(&cur[p >> 17], 1);
        csr_src[pos] = (int)(p & 0x1FFFFu);
    }
}

// ---------------- x16h prep: fp16( x[i,k]*dis[i] ), 0 pad -------------------
__global__ __launch_bounds__(256) void xprep_kernel(const float* __restrict__ x,
                                                    const float* __restrict__ dis,
                                                    __half* __restrict__ x16h, int N) {
    int gid = blockIdx.x * 256 + threadIdx.x;
    if (gid >= N * 16) return;
    int node = gid >> 4, k = gid & 15;
    float v = (k < 15) ? x[node * 15 + k] * dis[node] : 0.0f;
    x16h[gid] = __float2half(v);
}

// ---------------- gather16: aggx = P_hat*(x*dis)  (4 lanes x 8B per node) ---
__global__ __launch_bounds__(256) void gather16_kernel(const half4v* __restrict__ xh,
                                                       const int* __restrict__ csr_src,
                                                       const int* __restrict__ rowptr,
                                                       const float* __restrict__ dis,
                                                       float4* __restrict__ aggx, int N) {
    const int gid  = blockIdx.x * 256 + threadIdx.x;
    const int node = gid >> 2;
    if (node >= N) return;
    const int l  = threadIdx.x & 3;
    const int gb = threadIdx.x & 60;
    const int start = rowptr[node], end = rowptr[node + 1];
    const half2v ONEX = {(_Float16)1.0f, (_Float16)0.0f};
    const half2v ONEY = {(_Float16)0.0f, (_Float16)1.0f};
    float a0 = 0.0f, a1 = 0.0f, a2 = 0.0f, a3 = 0.0f;
    for (int j0 = start; j0 < end; j0 += 4) {
        int j   = j0 + l;
        int s   = (j < end) ? csr_src[j] : 0;
        int cnt = min(4, end - j0);
#pragma unroll
        for (int k = 0; k < 4; ++k) {
            int sk = __shfl(s, gb + k);
            if (k < cnt) {
                half4v v = xh[sk * 4 + l];
                half2v p0 = __builtin_shufflevector(v, v, 0, 1);
                half2v p1 = __builtin_shufflevector(v, v, 2, 3);
                a0 = FDOT2(p0, ONEX, a0);
                a1 = FDOT2(p0, ONEY, a1);
                a2 = FDOT2(p1, ONEX, a2);
                a3 = FDOT2(p1, ONEY, a3);
            }
        }
    }
    half4v sv = xh[node * 4 + l];
    half2v s0 = __builtin_shufflevector(sv, sv, 0, 1);
    half2v s1 = __builtin_shufflevector(sv, sv, 2, 3);
    a0 += (float)s0.x; a1 += (float)s0.y;
    a2 += (float)s1.x; a3 += (float)s1.y;
    float sn = dis[node];
    aggx[(size_t)node * 4 + l] = make_float4(sn * a0, sn * a1, sn * a2, sn * a3);
}

// ---------------- gemm12: th2 = fp16( relu(aggx@W1 + b1) @ W2 * dis ) -------
// fuses gemm1 + first gemmB via LDS h buffer (no h1pre round trip)
__global__ __launch_bounds__(256) void gemm12_kernel(const float* __restrict__ in,
                                                     const float* __restrict__ w1,
                                                     const float* __restrict__ b1,
                                                     const float* __restrict__ w2,
                                                     const float* __restrict__ dis,
                                                     __half* __restrict__ th_out, int N) {
    __shared__ float w1_s[16 * 64];   // 4 KB
    __shared__ float in_s[64 * 17];   // 4.3 KB
    __shared__ float w2_s[64 * 64];   // 16 KB
    __shared__ float h_s[64 * 65];    // 16.6 KB
    const int tid  = threadIdx.x;
    const int row0 = blockIdx.x * 64;
    const int rows = min(64, N - row0);

    for (int i = tid; i < 16 * 64; i += 256) w1_s[i] = (i < 15 * 64) ? w1[i] : 0.0f;
    for (int i = tid; i < 64 * 64; i += 256) w2_s[i] = w2[i];
    for (int i = tid; i < rows * 16; i += 256) {
        int r = i >> 4, k = i & 15;
        in_s[r * 17 + k] = in[(size_t)(row0 + r) * 16 + k];
    }
    __syncthreads();

    const int r  = tid & 63;
    const int cg = tid >> 6;
    {
        float acc[16];
#pragma unroll
        for (int i = 0; i < 16; ++i) acc[i] = 0.0f;
#pragma unroll
        for (int k = 0; k < 16; ++k) {
            float a = in_s[r * 17 + k];
#pragma unroll
            for (int cc = 0; cc < 16; ++cc)
                acc[cc] += a * w1_s[k * 64 + cg * 16 + cc];
        }
#pragma unroll
        for (int cc = 0; cc < 16; ++cc)
            h_s[r * 65 + cg * 16 + cc] = fmaxf(acc[cc] + b1[cg * 16 + cc], 0.0f);
    }
    __syncthreads();
    {
        const float2* w2v = reinterpret_cast<const float2*>(w2_s);
        float2 acc2[8];
#pragma unroll
        for (int i = 0; i < 8; ++i) acc2[i] = make_float2(0.0f, 0.0f);
#pragma unroll
        for (int k = 0; k < 64; ++k) {
            float a = h_s[r * 65 + k];
            const float2* wk = w2v + k * 32 + cg * 8;
#pragma unroll
            for (int i = 0; i < 8; ++i) {
                float2 wv = wk[i];
                acc2[i].x += a * wv.x;
                acc2[i].y += a * wv.y;
            }
        }
        const int row = row0 + r;
        if (row < N) {
            float sd = dis[row];
            __align__(16) __half2 hh[8];
#pragma unroll
            for (int i = 0; i < 8; ++i)
                hh[i] = __floats2half2_rn(acc2[i].x * sd, acc2[i].y * sd);
            float4* tp = reinterpret_cast<float4*>(th_out + (size_t)row * HID + cg * 16);
            tp[0] = reinterpret_cast<float4*>(hh)[0];
            tp[1] = reinterpret_cast<float4*>(hh)[1];
        }
    }
}

// ---------------- fusedGG: gather + GEMM in one pass ------------------------
// th_out[node,:] = fp16( dis*( relu( dis*(sum th_in[src,:] + self) + bias ) @ W ) )
// 8 nodes/block (32 lanes/node); row handoff via LDS
__global__ __launch_bounds__(256) void fusedGG_kernel(const half2v* __restrict__ th_in,
                                                      const int* __restrict__ csr_src,
                                                      const int* __restrict__ rowptr,
                                                      const float* __restrict__ dis,
                                                      const float* __restrict__ w,
                                                      const float* __restrict__ bias,
                                                      __half* __restrict__ th_out, int N) {
    __shared__ float w_s[64 * 64];    // 16 KB
    __shared__ float r_s[8][64];      // 2 KB
    const int tid = threadIdx.x;
    {   // stage W (row-major 64x64 fp32)
        const float4* wsrc = reinterpret_cast<const float4*>(w);
        float4* wdst = reinterpret_cast<float4*>(w_s);
        for (int i = tid; i < 1024; i += 256) wdst[i] = wsrc[i];
    }
    const int g    = tid >> 5;              // node slot 0..7
    const int node = blockIdx.x * 8 + g;
    const int l    = tid & 31;
    const int hb   = tid & 32;              // shfl base for this half-wave
    float u0 = 0.0f, u1 = 0.0f;
    if (node < N) {
        const int start = rowptr[node], end = rowptr[node + 1];
        const half2v* tl = th_in + l;
        const half2v ONEX = {(_Float16)1.0f, (_Float16)0.0f};
        const half2v ONEY = {(_Float16)0.0f, (_Float16)1.0f};
        float ax = 0.0f, ay = 0.0f;
        for (int j0 = start; j0 < end; j0 += 32) {
            int j   = j0 + l;
            int s   = (j < end) ? csr_src[j] : 0;
            int cnt = min(32, end - j0);
            int k = 0;
            for (; k + 16 <= cnt; k += 16) {
                int sk[16];
#pragma unroll
                for (int u = 0; u < 16; ++u) sk[u] = __shfl(s, hb + k + u);
                half2v v[16];
#pragma unroll
                for (int u = 0; u < 16; ++u) v[u] = tl[sk[u] * 32];
#pragma unroll
                for (int u = 0; u < 16; ++u) {
                    ax = FDOT2(v[u], ONEX, ax);
                    ay = FDOT2(v[u], ONEY, ay);
                }
            }
            for (; k + 4 <= cnt; k += 4) {
                int s0 = __shfl(s, hb + k);
                int s1 = __shfl(s, hb + k + 1);
                int s2 = __shfl(s, hb + k + 2);
                int s3 = __shfl(s, hb + k + 3);
                half2v v0 = tl[s0 * 32];
                half2v v1 = tl[s1 * 32];
                half2v v2 = tl[s2 * 32];
                half2v v3 = tl[s3 * 32];
                ax = FDOT2(v0, ONEX, ax); ay = FDOT2(v0, ONEY, ay);
                ax = FDOT2(v1, ONEX, ax); ay = FDOT2(v1, ONEY, ay);
                ax = FDOT2(v2, ONEX, ax); ay = FDOT2(v2, ONEY, ay);
                ax = FDOT2(v3, ONEX, ax); ay = FDOT2(v3, ONEY, ay);
            }
            for (; k < cnt; ++k) {
                half2v v = tl[__shfl(s, hb + k) * 32];
                ax += (float)v.x; ay += (float)v.y;
            }
        }
        half2v self = tl[node * 32];
        ax += (float)self.x; ay += (float)self.y;
        float sn = dis[node];
        float2 bv = reinterpret_cast<const float2*>(bias)[l];
        u0 = fmaxf(sn * ax + bv.x, 0.0f);
        u1 = fmaxf(sn * ay + bv.y, 0.0f);
    }
    reinterpret_cast<float2*>(r_s[g])[l] = make_float2(u0, u1);
    __syncthreads();
    if (node < N) {
        const float2* wv = reinterpret_cast<const float2*>(w_s);
        float c0 = 0.0f, c1 = 0.0f;
#pragma unroll 8
        for (int k = 0; k < 64; ++k) {
            float u = r_s[g][k];
            float2 ww = wv[k * 32 + l];
            c0 += u * ww.x;
            c1 += u * ww.y;
        }
        float sd = dis[node];
        reinterpret_cast<__half2*>(th_out)[(size_t)node * 32 + l] =
            __floats2half2_rn(c0 * sd, c1 * sd);
    }
}

// ---------------- gatherh (final layer): 32 lanes/node, fp32 out ------------
__global__ __launch_bounds__(256) void gatherh_kernel(const half2v* __restrict__ th,
                                                      const int* __restrict__ csr_src,
                                                      const int* __restrict__ rowptr,
                                                      const float* __restrict__ dis,
                                                      float* __restrict__ agg, int N) {
    const int gid  = blockIdx.x * 256 + threadIdx.x;
    const int node = gid >> 5;
    if (node >= N) return;
    const int l  = threadIdx.x & 31;
    const int hb = threadIdx.x & 32;
    const int start = rowptr[node], end = rowptr[node + 1];
    const half2v* tl = th + l;
    const half2v ONEX = {(_Float16)1.0f, (_Float16)0.0f};
    const half2v ONEY = {(_Float16)0.0f, (_Float16)1.0f};
    float ax = 0.0f, ay = 0.0f;
    for (int j0 = start; j0 < end; j0 += 32) {
        int j   = j0 + l;
        int s   = (j < end) ? csr_src[j] : 0;
        int cnt = min(32, end - j0);
        int k = 0;
        for (; k + 16 <= cnt; k += 16) {
            int sk[16];
#pragma unroll
            for (int u = 0; u < 16; ++u) sk[u] = __shfl(s, hb + k + u);
            half2v v[16];
#pragma unroll
            for (int u = 0; u < 16; ++u) v[u] = tl[sk[u] * 32];
#pragma unroll
            for (int u = 0; u < 16; ++u) {
                ax = FDOT2(v[u], ONEX, ax);
                ay = FDOT2(v[u], ONEY, ay);
            }
        }
        for (; k + 4 <= cnt; k += 4) {
            int s0 = __shfl(s, hb + k);
            int s1 = __shfl(s, hb + k + 1);
            int s2 = __shfl(s, hb + k + 2);
            int s3 = __shfl(s, hb + k + 3);
            half2v v0 = tl[s0 * 32];
            half2v v1 = tl[s1 * 32];
            half2v v2 = tl[s2 * 32];
            half2v v3 = tl[s3 * 32];
            ax = FDOT2(v0, ONEX, ax); ay = FDOT2(v0, ONEY, ay);
            ax = FDOT2(v1, ONEX, ax); ay = FDOT2(v1, ONEY, ay);
            ax = FDOT2(v2, ONEX, ax); ay = FDOT2(v2, ONEY, ay);
            ax = FDOT2(v3, ONEX, ax); ay = FDOT2(v3, ONEY, ay);
        }
        for (; k < cnt; ++k) {
            half2v v = tl[__shfl(s, hb + k) * 32];
            ax += (float)v.x; ay += (float)v.y;
        }
    }
    half2v self = tl[node * 32];
    ax += (float)self.x; ay += (float)self.y;
    float sn = dis[node];
    reinterpret_cast<float2*>(agg)[(size_t)node * 32 + l] =
        make_float2(sn * ax, sn * ay);
}

// ---------------- mean pool (batch is sorted) ------------------------------
__global__ __launch_bounds__(256) void pool_kernel(const float* __restrict__ agg,
                                                   const float* __restrict__ b4,
                                                   const int* __restrict__ batch,
                                                   float* __restrict__ sums,
                                                   float* __restrict__ cnts, int N) {
    __shared__ float lsum[NG * HID];
    __shared__ float lcnt[NG];
    const int tid  = threadIdx.x;
    const int base = blockIdx.x * 256;
    const int last = min(base + 256, N) - 1;
    const int gfirst = batch[base];
    const int glast  = batch[last];
    const int span   = glast - gfirst + 1;

    for (int i = tid; i < span * HID; i += 256) lsum[i] = 0.0f;
    for (int i = tid; i < span; i += 256) lcnt[i] = 0.0f;
    __syncthreads();

    const int f = tid & 63, sub = tid >> 6;
    for (int n = base + sub; n < min(base + 256, N); n += 4) {
        int g = batch[n];
        float v = fmaxf(agg[(size_t)n * HID + f] + b4[f], 0.0f);
        atomicAdd(&lsum[(g - gfirst) * HID + f], v);
        if (f == 0) atomicAdd(&lcnt[g - gfirst], 1.0f);
    }
    __syncthreads();

    for (int i = tid; i < span * HID; i += 256)
        atomicAdd(&sums[(size_t)gfirst * HID + i], lsum[i]);
    for (int i = tid; i < span; i += 256) atomicAdd(&cnts[gfirst + i], lcnt[i]);
}

__global__ __launch_bounds__(256) void finalize_kernel(const float* __restrict__ sums,
                                                       const float* __restrict__ cnts,
                                                       float* __restrict__ out) {
    int i = blockIdx.x * 256 + threadIdx.x;
    if (i < NG * HID) out[i] = sums[i] / fmaxf(cnts[i >> 6], 1.0f);
}

// ---------------- launch ----------------
extern "C" void kernel_launch(void* const* d_in, const int* in_sizes, int n_in,
                              void* d_out, int out_size, void* d_ws, size_t ws_size,
                              hipStream_t stream) {
    const float* x  = (const float*)d_in[0];
    const float* w1 = (const float*)d_in[1];
    const float* b1 = (const float*)d_in[2];
    const float* w2 = (const float*)d_in[3];
    const float* b2 = (const float*)d_in[4];
    const float* w3 = (const float*)d_in[5];
    const float* b3 = (const float*)d_in[6];
    const float* w4 = (const float*)d_in[7];
    const float* b4 = (const float*)d_in[8];
    const int* ei    = (const int*)d_in[9];
    const int* batch = (const int*)d_in[10];
    const int* src = ei;
    const int* dst = ei + NE;

    // workspace layout (~64.9 MB):
    //   AGG 25.6 MB fp32; its first 12.8 MB doubles as thB (th3, dead before
    //   gatherh writes AGG). thA 12.8 MB separate (th2 then th4).
    //   pairs 12.8 MB (dead after csr) overlaid by x16h(3.2)+aggx(6.4).
    float*    AGG     = (float*)d_ws;                        // NN*HID fp32
    __half*   thB     = (__half*)d_ws;                       // alias AGG[0..12.8MB)
    __half*   thA     = (__half*)(AGG + (size_t)NN * HID);   // 12.8 MB
    unsigned* pairs   = (unsigned*)(thA + (size_t)NN * HID); // 12.8 MB region
    __half*   x16h    = (__half*)pairs;                      // 3.2 MB (alias)
    float*    aggx    = (float*)(x16h + (size_t)NN * 16);    // 6.4 MB (alias)
    int*      csr_src = (int*)((char*)pairs + (size_t)NE * 4); // 12.8 MB
    int*      rowptr  = csr_src + NE;                        // NN+1
    float*    dis     = (float*)(rowptr + NN + 1);           // NN
    int*      bcnt    = (int*)(dis + NN);                    // NBK
    int*      bbase   = bcnt + NBK;                          // NBK+1
    int*      bcur    = bbase + NBK + 1;                     // NBK
    float*    sums    = (float*)(bcur + NBK);                // NG*HID
    float*    cnts    = sums + NG * HID;                     // NG

    float* out = (float*)d_out;

    const int NB  = (NN + 255) / 256;
    const int GB  = (NN + 63) / 64;
    const int XB  = (NN * 16 + 255) / 256;   // xprep
    const int OB  = (NN * 4 + 255) / 256;    // gather16: 4 lanes/node
    const int HB  = (NN * 32 + 255) / 256;   // gatherh: 32 lanes/node
    const int FB  = (NN + 7) / 8;            // fusedGG: 8 nodes/block
    const int CB  = (NE + CCH - 1) / CCH;

    hipMemsetAsync(bcnt, 0, NBK * sizeof(int), stream);
    hipMemsetAsync(sums, 0, (NG * HID + NG) * sizeof(float), stream);

    bcount_kernel<<<512, 256, 0, stream>>>(dst, bcnt, NE);
    bscan_kernel<<<1, 256, 0, stream>>>(bcnt, bbase, bcur, NE);
    bscatter_kernel<<<CB, 256, 0, stream>>>(src, dst, bcur, pairs, NE);
    csr_kernel<<<NBK, 256, 0, stream>>>(pairs, bbase, rowptr, csr_src, dis, NN, NE);

    // layer 1 (commuted) + layer-2 linear, fused: th2 = f(P x)
    xprep_kernel<<<XB, 256, 0, stream>>>(x, dis, x16h, NN);
    gather16_kernel<<<OB, 256, 0, stream>>>((const half4v*)x16h, csr_src, rowptr, dis,
                                            (float4*)aggx, NN);
    gemm12_kernel<<<GB, 256, 0, stream>>>(aggx, w1, b1, w2, dis, thA, NN);
    // layers 2->3, 3->4 fused gather+GEMM
    fusedGG_kernel<<<FB, 256, 0, stream>>>((const half2v*)thA, csr_src, rowptr, dis,
                                           w3, b2, thB, NN);
    fusedGG_kernel<<<FB, 256, 0, stream>>>((const half2v*)thB, csr_src, rowptr, dis,
                                           w4, b3, thA, NN);
    // final gather (layer 4 aggregation), fp32 out for pool
    gatherh_kernel<<<HB, 256, 0, stream>>>((const half2v*)thA, csr_src, rowptr, dis, AGG, NN);

    pool_kernel<<<NB, 256, 0, stream>>>(AGG, b4, batch, sums, cnts, NN);
    finalize_kernel<<<(NG * HID + 255) / 256, 256, 0, stream>>>(sums, cnts, out);
}